// Round 13
// baseline (1288.962 us; speedup 1.0000x reference)
//
#include <hip/hip_runtime.h>
#include <hip/hip_bf16.h>
#include <cstdint>
#include <cstddef>

#define N_NODES 100000
#define N_EDGES 1600000
#define EMBD 128
#define HID 256
#define N_GRAPHS 128
#define VOCAB 1000
#define NB_SCAN 98   // ceil(N_NODES/1024)

typedef short bf16x8 __attribute__((ext_vector_type(8)));
typedef float f32x4 __attribute__((ext_vector_type(4)));
typedef float f32x2 __attribute__((ext_vector_type(2)));

__device__ inline unsigned short rne_bf16(float f) {
  unsigned u = __float_as_uint(f);
  return (unsigned short)((u + 0x7FFFu + ((u >> 16) & 1u)) >> 16);
}
__device__ inline float bf16_to_f32(unsigned short h) {
  return __uint_as_float(((unsigned)h) << 16);
}
__device__ inline void split_hl(float v, unsigned short& h, unsigned short& l) {
  h = rne_bf16(v);
  float hf = __uint_as_float(((unsigned)h) << 16);
  l = rne_bf16(v - hf);
}
__device__ inline f32x4 cvt4(uint2 v) {
  f32x4 r;
  r[0] = __uint_as_float(v.x << 16);
  r[1] = __uint_as_float(v.x & 0xFFFF0000u);
  r[2] = __uint_as_float(v.y << 16);
  r[3] = __uint_as_float(v.y & 0xFFFF0000u);
  return r;
}
__device__ inline f32x2 cvt2(unsigned v) {
  f32x2 r;
  r[0] = __uint_as_float(v << 16);
  r[1] = __uint_as_float(v & 0xFFFF0000u);
  return r;
}

// ---------------- CSR build ----------------
__global__ void k_indeg(const int* __restrict__ dst, int* __restrict__ indeg) {
  int e = blockIdx.x * 256 + threadIdx.x;
  if (e < N_EDGES) atomicAdd(&indeg[dst[e]], 1);
}

__global__ __launch_bounds__(1024)
void k_scan1(const int* __restrict__ indeg, int* __restrict__ off, int* __restrict__ bsum,
             float* __restrict__ dis) {
  __shared__ int s[1024];
  const int tid = threadIdx.x;
  int i = blockIdx.x * 1024 + tid;
  int v = (i < N_NODES) ? indeg[i] : 0;
  if (i < N_NODES) dis[i] = rsqrtf((float)(v + 1));   // fused degree-norm
  s[tid] = v; __syncthreads();
  #pragma unroll
  for (int ofs = 1; ofs < 1024; ofs <<= 1) {
    int t2 = (tid >= ofs) ? s[tid - ofs] : 0;
    __syncthreads();
    s[tid] += t2;
    __syncthreads();
  }
  if (i < N_NODES) off[i] = s[tid] - v;      // exclusive within block
  if (tid == 1023) bsum[blockIdx.x] = s[1023];
}

// wave/block-parallel scan of the 98 block sums (was a serial 1-thread loop ~50us)
__global__ void k_scan2(int* __restrict__ bsum) {
  __shared__ int s[128];
  const int t = threadIdx.x;
  int v = (t < NB_SCAN) ? bsum[t] : 0;
  s[t] = v; __syncthreads();
  #pragma unroll
  for (int ofs = 1; ofs < 128; ofs <<= 1) {
    int x = (t >= ofs) ? s[t - ofs] : 0;
    __syncthreads();
    s[t] += x;
    __syncthreads();
  }
  if (t < NB_SCAN) bsum[t] = s[t] - v;
  if (t == 127) bsum[NB_SCAN] = s[127];
}

__global__ __launch_bounds__(1024)
void k_scan3(int* __restrict__ off, int* __restrict__ cur, const int* __restrict__ bsum) {
  int i = blockIdx.x * 1024 + threadIdx.x;
  if (i < N_NODES) { int v = off[i] + bsum[blockIdx.x]; off[i] = v; cur[i] = v; }
  if (i == 0) off[N_NODES] = bsum[NB_SCAN];
}

__global__ void k_fill(const int* __restrict__ src, const int* __restrict__ dst,
                       const int* __restrict__ ids, const float* __restrict__ dis,
                       int* __restrict__ cursor, int2* __restrict__ csre,
                       int2* __restrict__ csre0) {
  int e = blockIdx.x * 256 + threadIdx.x;
  if (e < N_EDGES) {
    int s = src[e];
    float ds = dis[s];
    int p = atomicAdd(&cursor[dst[e]], 1);
    csre[p]  = make_int2(s, __float_as_int(ds));
    csre0[p] = make_int2(ids[s], __float_as_int(ds));
  }
}

// ---------------- fused prep: emb->bf16 + W transpose/split ----------------
__global__ void k_prep(const float* __restrict__ emb, unsigned short* __restrict__ emb16,
                       const float* __restrict__ W0, unsigned short* __restrict__ w0h,
                       unsigned short* __restrict__ w0l,
                       const float* __restrict__ W1, unsigned short* __restrict__ w1h,
                       unsigned short* __restrict__ w1l,
                       const float* __restrict__ W2, unsigned short* __restrict__ w2h,
                       unsigned short* __restrict__ w2l,
                       const float* __restrict__ W3, unsigned short* __restrict__ w3h,
                       unsigned short* __restrict__ w3l) {
  int i = blockIdx.x * 256 + threadIdx.x;
  if (i < VOCAB * EMBD) { emb16[i] = rne_bf16(emb[i]); return; }
  i -= VOCAB * EMBD;
  unsigned short h, l;
  if (i < EMBD * HID) {               // W0: [128][256] -> [256][128] split
    int k = i >> 8, n = i & 255;
    split_hl(W0[i], h, l);
    w0h[n * EMBD + k] = h; w0l[n * EMBD + k] = l;
    return;
  }
  i -= EMBD * HID;
  if (i >= 3 * HID * HID) return;
  int w = i >> 16, j = i & 65535;     // W1..W3: [256][256] -> [256][256] split
  const float* Ws = (w == 0) ? W1 : (w == 1) ? W2 : W3;
  unsigned short* th = (w == 0) ? w1h : (w == 1) ? w2h : w3h;
  unsigned short* tl = (w == 0) ? w1l : (w == 1) ? w2l : w3l;
  int k = j >> 8, n = j & 255;
  split_hl(Ws[j], h, l);
  th[n * HID + k] = h; tl[n * HID + k] = l;
}

// ---------------- fused layer: gather-aggregate -> LDS -> MFMA GEMM ----------------
// Block: 64 output rows x all 256 cols; 4 waves. Phase 1: each wave aggregates
// 16 nodes (f32 accum, identical order to the standalone agg kernels) and writes
// bf16 rows to a padded LDS tile [64][K+8] (pad -> <=2-way bank alias = free).
// Phase 2: GEMM from LDS A + L2-resident W (hi/lo split, 2 MFMA products).
// K==256: xin = y_prev [N][256]. K==128: xin = emb16, self row via ids[node].
template<int K>
__global__ __launch_bounds__(256)
void k_fused(const unsigned short* __restrict__ xin, const int* __restrict__ ids,
             const float* __restrict__ dis, const int* __restrict__ off,
             const int2* __restrict__ csre,
             const unsigned short* __restrict__ Wh, const unsigned short* __restrict__ Wl,
             const float* __restrict__ bias, unsigned short* __restrict__ yout) {
  constexpr int LDA = K + 8;
  __shared__ unsigned short sA[64 * LDA];
  const int tid = threadIdx.x;
  const int lane = tid & 63;
  const int wid = tid >> 6;
  const int row0 = blockIdx.x * 64;

  // ---- phase 1: gather + aggregate ----
  for (int n = 0; n < 16; ++n) {
    const int lrow = wid * 16 + n;
    const int node = row0 + lrow;
    if constexpr (K == 256) {
      f32x4 a0 = (f32x4)0.f, a1 = (f32x4)0.f, a2 = (f32x4)0.f, a3 = (f32x4)0.f;
      if (node < N_NODES) {
        const float di = dis[node];
        uint2 sv = *((const uint2*)(xin + (size_t)node * 256) + lane);
        a0 = di * cvt4(sv);
        const int e0 = off[node], e1 = off[node + 1];
        int e = e0;
        for (; e + 4 <= e1; e += 4) {
          int2 c0 = csre[e], c1 = csre[e + 1], c2 = csre[e + 2], c3 = csre[e + 3];
          uint2 v0 = *((const uint2*)(xin + (size_t)c0.x * 256) + lane);
          uint2 v1 = *((const uint2*)(xin + (size_t)c1.x * 256) + lane);
          uint2 v2 = *((const uint2*)(xin + (size_t)c2.x * 256) + lane);
          uint2 v3 = *((const uint2*)(xin + (size_t)c3.x * 256) + lane);
          a0 += __int_as_float(c0.y) * cvt4(v0);
          a1 += __int_as_float(c1.y) * cvt4(v1);
          a2 += __int_as_float(c2.y) * cvt4(v2);
          a3 += __int_as_float(c3.y) * cvt4(v3);
        }
        for (; e < e1; ++e) {
          int2 c0 = csre[e];
          uint2 v0 = *((const uint2*)(xin + (size_t)c0.x * 256) + lane);
          a0 += __int_as_float(c0.y) * cvt4(v0);
        }
        f32x4 r = di * ((a0 + a1) + (a2 + a3));
        *(ushort4*)&sA[lrow * LDA + lane * 4] =
            make_ushort4(rne_bf16(r[0]), rne_bf16(r[1]), rne_bf16(r[2]), rne_bf16(r[3]));
      } else {
        *(ushort4*)&sA[lrow * LDA + lane * 4] = make_ushort4(0, 0, 0, 0);
      }
    } else {   // K == 128: emb16 gather
      f32x2 a0 = (f32x2)0.f, a1 = (f32x2)0.f, a2 = (f32x2)0.f, a3 = (f32x2)0.f;
      if (node < N_NODES) {
        const float di = dis[node];
        unsigned sv = *((const unsigned*)(xin + (size_t)ids[node] * 128) + lane);
        a0 = di * cvt2(sv);
        const int e0 = off[node], e1 = off[node + 1];
        int e = e0;
        for (; e + 4 <= e1; e += 4) {
          int2 c0 = csre[e], c1 = csre[e + 1], c2 = csre[e + 2], c3 = csre[e + 3];
          unsigned v0 = *((const unsigned*)(xin + (size_t)c0.x * 128) + lane);
          unsigned v1 = *((const unsigned*)(xin + (size_t)c1.x * 128) + lane);
          unsigned v2 = *((const unsigned*)(xin + (size_t)c2.x * 128) + lane);
          unsigned v3 = *((const unsigned*)(xin + (size_t)c3.x * 128) + lane);
          a0 += __int_as_float(c0.y) * cvt2(v0);
          a1 += __int_as_float(c1.y) * cvt2(v1);
          a2 += __int_as_float(c2.y) * cvt2(v2);
          a3 += __int_as_float(c3.y) * cvt2(v3);
        }
        for (; e < e1; ++e) {
          int2 c0 = csre[e];
          unsigned v0 = *((const unsigned*)(xin + (size_t)c0.x * 128) + lane);
          a0 += __int_as_float(c0.y) * cvt2(v0);
        }
        f32x2 r = di * ((a0 + a1) + (a2 + a3));
        *(ushort2*)&sA[lrow * LDA + lane * 2] = make_ushort2(rne_bf16(r[0]), rne_bf16(r[1]));
      } else {
        *(ushort2*)&sA[lrow * LDA + lane * 2] = make_ushort2(0, 0);
      }
    }
  }
  __syncthreads();

  // ---- phase 2: GEMM 64 rows x 64 cols per wave (wave wid -> cols wid*64..) ----
  const int cl = lane & 15;
  const int sl = lane >> 4;
  f32x4 acc[4][4];
  #pragma unroll
  for (int i = 0; i < 4; ++i)
    #pragma unroll
    for (int j = 0; j < 4; ++j) acc[i][j] = (f32x4)0.f;

  for (int kt = 0; kt < K; kt += 32) {
    bf16x8 fa[4], fbh[4], fbl[4];
    #pragma unroll
    for (int f = 0; f < 4; ++f) {
      fa[f]  = *(const bf16x8*)&sA[(f * 16 + cl) * LDA + kt + sl * 8];
      int wrow = wid * 64 + f * 16 + cl;     // W row = output col
      fbh[f] = *(const bf16x8*)&Wh[(size_t)wrow * K + kt + sl * 8];
      fbl[f] = *(const bf16x8*)&Wl[(size_t)wrow * K + kt + sl * 8];
    }
    #pragma unroll
    for (int i = 0; i < 4; ++i)
      #pragma unroll
      for (int j = 0; j < 4; ++j) {
        acc[i][j] = __builtin_amdgcn_mfma_f32_16x16x32_bf16(fa[i], fbh[j], acc[i][j], 0, 0, 0);
        acc[i][j] = __builtin_amdgcn_mfma_f32_16x16x32_bf16(fa[i], fbl[j], acc[i][j], 0, 0, 0);
      }
  }

  // ---- epilogue: bias + relu, bf16 store ----
  #pragma unroll
  for (int j = 0; j < 4; ++j) {
    int gn = wid * 64 + j * 16 + cl;
    float bn = bias[gn];
    #pragma unroll
    for (int i = 0; i < 4; ++i) {
      f32x4 v = acc[i][j];
      #pragma unroll
      for (int r = 0; r < 4; ++r) {
        int gm = row0 + i * 16 + sl * 4 + r;
        if (gm < N_NODES) yout[(size_t)gm * HID + gn] = rne_bf16(fmaxf(v[r] + bn, 0.f));
      }
    }
  }
}

// ---------------- pooling: 4 row-chunks per graph, atomic combine ----------------
__device__ inline int lower_bound_i(const int* a, int n, int v) {
  int lo = 0, hi = n;
  while (lo < hi) { int m = (lo + hi) >> 1; if (a[m] < v) lo = m + 1; else hi = m; }
  return lo;
}

__global__ __launch_bounds__(256)
void k_pool(const unsigned short* __restrict__ y16, const int* __restrict__ batch,
            float* __restrict__ gsum, float* __restrict__ gmax) {
  const int gi = blockIdx.x, ck = blockIdx.y, t = threadIdx.x;
  const int start = lower_bound_i(batch, N_NODES, gi);
  const int end   = lower_bound_i(batch, N_NODES, gi + 1);
  const int len = end - start;
  const int c0 = start + (len * ck) / 4;
  const int c1 = start + (len * (ck + 1)) / 4;
  float sum = 0.f, mx = 0.f;     // post-relu >= 0
  #pragma unroll 4
  for (int n = c0; n < c1; ++n) {
    float v = bf16_to_f32(y16[(size_t)n * HID + t]);
    sum += v; mx = fmaxf(mx, v);
  }
  if (c0 < c1) {
    atomicAdd(&gsum[gi * HID + t], sum);
    atomicMax((int*)&gmax[gi * HID + t], __float_as_int(mx));  // valid: mx >= 0
  }
}

// ---------------- classifier head ----------------
__global__ __launch_bounds__(256)
void k_cls(const float* __restrict__ gsum, const float* __restrict__ gmax,
           const int* __restrict__ batch,
           const float* __restrict__ Wc1, const float* __restrict__ bc1,
           const float* __restrict__ Wc2, const float* __restrict__ bc2,
           float* __restrict__ out) {
  const int gi = blockIdx.x, t = threadIdx.x;
  __shared__ float sg[512];
  __shared__ float sh[256];
  const int start = lower_bound_i(batch, N_NODES, gi);
  const int end   = lower_bound_i(batch, N_NODES, gi + 1);
  const float rcnt = 1.f / (float)((end - start) > 0 ? (end - start) : 1);
  sg[t] = gsum[gi * HID + t] * rcnt;
  sg[256 + t] = gmax[gi * HID + t];
  __syncthreads();
  float a = bc1[t];
  #pragma unroll 8
  for (int k = 0; k < 512; ++k) a = fmaf(sg[k], Wc1[k * HID + t], a);
  sh[t] = fmaxf(a, 0.f);
  __syncthreads();
  if (t < 2) {
    float o = bc2[t];
    for (int k = 0; k < 256; ++k) o = fmaf(sh[k], Wc2[k * 2 + t], o);
    out[gi * 2 + t] = o;
  }
}

// ---------------- launch ----------------
extern "C" void kernel_launch(void* const* d_in, const int* in_sizes, int n_in,
                              void* d_out, int out_size, void* d_ws, size_t ws_size,
                              hipStream_t stream) {
  const int*   x_ids = (const int*)d_in[0];
  const int*   ei    = (const int*)d_in[1];
  const int*   batch = (const int*)d_in[2];
  const float* emb   = (const float*)d_in[3];
  const float* W0 = (const float*)d_in[4];  const float* b0 = (const float*)d_in[5];
  const float* W1 = (const float*)d_in[6];  const float* b1 = (const float*)d_in[7];
  const float* W2 = (const float*)d_in[8];  const float* b2 = (const float*)d_in[9];
  const float* W3 = (const float*)d_in[10]; const float* b3 = (const float*)d_in[11];
  const float* Wc1 = (const float*)d_in[12]; const float* bc1 = (const float*)d_in[13];
  const float* Wc2 = (const float*)d_in[14]; const float* bc2 = (const float*)d_in[15];
  float* out = (float*)d_out;
  const int* src = ei;
  const int* dst = ei + N_EDGES;

  char* ws = (char*)d_ws;
  size_t o = 0;
  auto alloc = [&](size_t bytes) -> char* {
    char* p = ws + o; o += (bytes + 255) & ~(size_t)255; return p;
  };
  unsigned short* yA   = (unsigned short*)alloc((size_t)N_NODES * HID * 2);
  unsigned short* yB   = (unsigned short*)alloc((size_t)N_NODES * HID * 2);
  float* dis   = (float*)alloc((size_t)N_NODES * 4);
  int*   indeg = (int*)  alloc((size_t)N_NODES * 4);
  int*   off   = (int*)  alloc((size_t)(N_NODES + 1) * 4);
  int*   cur   = (int*)  alloc((size_t)(N_NODES + 1) * 4);
  int*   bsum  = (int*)  alloc((size_t)(NB_SCAN + 1) * 4);
  int2*  csre  = (int2*) alloc((size_t)N_EDGES * 8);
  int2*  csre0 = (int2*) alloc((size_t)N_EDGES * 8);
  unsigned short* emb16 = (unsigned short*)alloc((size_t)VOCAB * EMBD * 2);
  unsigned short* wbuf  = (unsigned short*)alloc((size_t)458752 * 2);
  float* gsum  = (float*)alloc((size_t)N_GRAPHS * HID * 4);
  float* gmax  = (float*)alloc((size_t)N_GRAPHS * HID * 4);
  (void)ws_size; (void)in_sizes; (void)n_in; (void)out_size;

  unsigned short* wt0h = wbuf;            unsigned short* wt0l = wbuf + 32768;
  unsigned short* wt1h = wbuf + 65536;    unsigned short* wt1l = wbuf + 131072;
  unsigned short* wt2h = wbuf + 196608;   unsigned short* wt2l = wbuf + 262144;
  unsigned short* wt3h = wbuf + 327680;   unsigned short* wt3l = wbuf + 393216;

  hipMemsetAsync(indeg, 0, (size_t)N_NODES * 4, stream);
  hipMemsetAsync(gsum, 0, (size_t)N_GRAPHS * HID * 4 * 2, stream);   // gsum+gmax contiguous
  k_indeg<<<N_EDGES / 256, 256, 0, stream>>>(dst, indeg);
  k_scan1<<<NB_SCAN, 1024, 0, stream>>>(indeg, off, bsum, dis);
  k_scan2<<<1, 128, 0, stream>>>(bsum);
  k_scan3<<<NB_SCAN, 1024, 0, stream>>>(off, cur, bsum);
  k_fill<<<N_EDGES / 256, 256, 0, stream>>>(src, dst, x_ids, dis, cur, csre, csre0);
  k_prep<<<(VOCAB * EMBD + EMBD * HID + 3 * HID * HID + 255) / 256, 256, 0, stream>>>(
      emb, emb16, W0, wt0h, wt0l, W1, wt1h, wt1l, W2, wt2h, wt2l, W3, wt3h, wt3l);

  const int nblk = (N_NODES + 63) / 64;    // 1563
  // layer 0: gather L2-resident emb16 (via ids) -> GEMM K=128 -> yA
  k_fused<128><<<nblk, 256, 0, stream>>>(emb16, x_ids, dis, off, csre0, wt0h, wt0l, b0, yA);
  // layers 1..3: gather bf16 activations -> GEMM K=256, ping-pong
  k_fused<256><<<nblk, 256, 0, stream>>>(yA, nullptr, dis, off, csre, wt1h, wt1l, b1, yB);
  k_fused<256><<<nblk, 256, 0, stream>>>(yB, nullptr, dis, off, csre, wt2h, wt2l, b2, yA);
  k_fused<256><<<nblk, 256, 0, stream>>>(yA, nullptr, dis, off, csre, wt3h, wt3l, b3, yB);

  dim3 pgrid(N_GRAPHS, 4);
  k_pool<<<pgrid, 256, 0, stream>>>(yB, batch, gsum, gmax);
  k_cls<<<N_GRAPHS, 256, 0, stream>>>(gsum, gmax, batch, Wc1, bc1, Wc2, bc2, out);
}

// Round 14
// 976.923 us; speedup vs baseline: 1.3194x; 1.3194x over previous
//
#include <hip/hip_runtime.h>
#include <hip/hip_bf16.h>
#include <cstdint>
#include <cstddef>

#define N_NODES 100000
#define N_EDGES 1600000
#define EMBD 128
#define HID 256
#define N_GRAPHS 128
#define VOCAB 1000
#define NB_SCAN 98   // ceil(N_NODES/1024)

typedef short bf16x8 __attribute__((ext_vector_type(8)));
typedef float f32x4 __attribute__((ext_vector_type(4)));
typedef float f32x2 __attribute__((ext_vector_type(2)));

__device__ inline unsigned short rne_bf16(float f) {
  unsigned u = __float_as_uint(f);
  return (unsigned short)((u + 0x7FFFu + ((u >> 16) & 1u)) >> 16);
}
__device__ inline float bf16_to_f32(unsigned short h) {
  return __uint_as_float(((unsigned)h) << 16);
}
__device__ inline void split_hl(float v, unsigned short& h, unsigned short& l) {
  h = rne_bf16(v);
  float hf = __uint_as_float(((unsigned)h) << 16);
  l = rne_bf16(v - hf);
}
__device__ inline f32x4 cvt4(uint2 v) {
  f32x4 r;
  r[0] = __uint_as_float(v.x << 16);
  r[1] = __uint_as_float(v.x & 0xFFFF0000u);
  r[2] = __uint_as_float(v.y << 16);
  r[3] = __uint_as_float(v.y & 0xFFFF0000u);
  return r;
}
__device__ inline f32x2 cvt2(unsigned v) {
  f32x2 r;
  r[0] = __uint_as_float(v << 16);
  r[1] = __uint_as_float(v & 0xFFFF0000u);
  return r;
}

// ---------------- CSR build ----------------
__global__ void k_indeg(const int* __restrict__ dst, int* __restrict__ indeg) {
  int e = blockIdx.x * 256 + threadIdx.x;
  if (e < N_EDGES) atomicAdd(&indeg[dst[e]], 1);
}

__global__ __launch_bounds__(1024)
void k_scan1(const int* __restrict__ indeg, int* __restrict__ off, int* __restrict__ bsum,
             float* __restrict__ dis) {
  __shared__ int s[1024];
  const int tid = threadIdx.x;
  int i = blockIdx.x * 1024 + tid;
  int v = (i < N_NODES) ? indeg[i] : 0;
  if (i < N_NODES) dis[i] = rsqrtf((float)(v + 1));   // fused degree-norm
  s[tid] = v; __syncthreads();
  #pragma unroll
  for (int ofs = 1; ofs < 1024; ofs <<= 1) {
    int t2 = (tid >= ofs) ? s[tid - ofs] : 0;
    __syncthreads();
    s[tid] += t2;
    __syncthreads();
  }
  if (i < N_NODES) off[i] = s[tid] - v;      // exclusive within block
  if (tid == 1023) bsum[blockIdx.x] = s[1023];
}

// block-parallel scan of the 98 block sums (serial 1-thread loop was ~30-50us)
__global__ void k_scan2(int* __restrict__ bsum) {
  __shared__ int s[128];
  const int t = threadIdx.x;
  int v = (t < NB_SCAN) ? bsum[t] : 0;
  s[t] = v; __syncthreads();
  #pragma unroll
  for (int ofs = 1; ofs < 128; ofs <<= 1) {
    int x = (t >= ofs) ? s[t - ofs] : 0;
    __syncthreads();
    s[t] += x;
    __syncthreads();
  }
  if (t < NB_SCAN) bsum[t] = s[t] - v;
  if (t == 127) bsum[NB_SCAN] = s[127];
}

__global__ __launch_bounds__(1024)
void k_scan3(int* __restrict__ off, int* __restrict__ cur, const int* __restrict__ bsum) {
  int i = blockIdx.x * 1024 + threadIdx.x;
  if (i < N_NODES) { int v = off[i] + bsum[blockIdx.x]; off[i] = v; cur[i] = v; }
  if (i == 0) off[N_NODES] = bsum[NB_SCAN];
}

// single CSR array: (src, dis[src]) — csre0/ids variant removed (halves the
// scattered write-allocate traffic that dominated this kernel)
__global__ void k_fill(const int* __restrict__ src, const int* __restrict__ dst,
                       const float* __restrict__ dis,
                       int* __restrict__ cursor, int2* __restrict__ csre) {
  int e = blockIdx.x * 256 + threadIdx.x;
  if (e < N_EDGES) {
    int s = src[e];
    float ds = dis[s];
    int p = atomicAdd(&cursor[dst[e]], 1);
    csre[p] = make_int2(s, __float_as_int(ds));
  }
}

// ---------------- fused prep: emb->bf16 + W transpose/split ----------------
__global__ void k_prep(const float* __restrict__ emb, unsigned short* __restrict__ emb16,
                       const float* __restrict__ W0, unsigned short* __restrict__ w0h,
                       unsigned short* __restrict__ w0l,
                       const float* __restrict__ W1, unsigned short* __restrict__ w1h,
                       unsigned short* __restrict__ w1l,
                       const float* __restrict__ W2, unsigned short* __restrict__ w2h,
                       unsigned short* __restrict__ w2l,
                       const float* __restrict__ W3, unsigned short* __restrict__ w3h,
                       unsigned short* __restrict__ w3l) {
  int i = blockIdx.x * 256 + threadIdx.x;
  if (i < VOCAB * EMBD) { emb16[i] = rne_bf16(emb[i]); return; }
  i -= VOCAB * EMBD;
  unsigned short h, l;
  if (i < EMBD * HID) {               // W0: [128][256] -> [256][128] split
    int k = i >> 8, n = i & 255;
    split_hl(W0[i], h, l);
    w0h[n * EMBD + k] = h; w0l[n * EMBD + k] = l;
    return;
  }
  i -= EMBD * HID;
  if (i >= 3 * HID * HID) return;
  int w = i >> 16, j = i & 65535;     // W1..W3: [256][256] -> [256][256] split
  const float* Ws = (w == 0) ? W1 : (w == 1) ? W2 : W3;
  unsigned short* th = (w == 0) ? w1h : (w == 1) ? w2h : w3h;
  unsigned short* tl = (w == 0) ? w1l : (w == 1) ? w2l : w3l;
  int k = j >> 8, n = j & 255;
  split_hl(Ws[j], h, l);
  th[n * HID + k] = h; tl[n * HID + k] = l;
}

// ---------------- layer-0 aggregation: csre -> ids (L2) -> emb16 row (L2) ----------------
__global__ __launch_bounds__(256)
void k_agg0(const unsigned short* __restrict__ emb16, const int* __restrict__ ids,
            const float* __restrict__ dis, const int* __restrict__ off,
            const int2* __restrict__ csre, unsigned short* __restrict__ aggA) {
  const int lane = threadIdx.x & 63;
  const int node = blockIdx.x * 4 + (threadIdx.x >> 6);  // wave per node
  const float di = dis[node];
  unsigned sv = *((const unsigned*)(emb16 + (size_t)ids[node] * EMBD) + lane);
  f32x2 a0 = di * cvt2(sv);
  f32x2 a1 = (f32x2)0.f, a2 = (f32x2)0.f, a3 = (f32x2)0.f;
  const int e0 = off[node], e1 = off[node + 1];
  int e = e0;
  for (; e + 4 <= e1; e += 4) {
    int2 c0 = csre[e], c1 = csre[e + 1], c2 = csre[e + 2], c3 = csre[e + 3];
    int i0 = ids[c0.x], i1 = ids[c1.x], i2 = ids[c2.x], i3 = ids[c3.x];
    unsigned v0 = *((const unsigned*)(emb16 + (size_t)i0 * EMBD) + lane);
    unsigned v1 = *((const unsigned*)(emb16 + (size_t)i1 * EMBD) + lane);
    unsigned v2 = *((const unsigned*)(emb16 + (size_t)i2 * EMBD) + lane);
    unsigned v3 = *((const unsigned*)(emb16 + (size_t)i3 * EMBD) + lane);
    a0 += __int_as_float(c0.y) * cvt2(v0);
    a1 += __int_as_float(c1.y) * cvt2(v1);
    a2 += __int_as_float(c2.y) * cvt2(v2);
    a3 += __int_as_float(c3.y) * cvt2(v3);
  }
  for (; e < e1; ++e) {
    int2 c0 = csre[e];
    unsigned v0 = *((const unsigned*)(emb16 + (size_t)ids[c0.x] * EMBD) + lane);
    a0 += __int_as_float(c0.y) * cvt2(v0);
  }
  f32x2 r = di * ((a0 + a1) + (a2 + a3));
  size_t base = (size_t)node * EMBD + lane * 2;
  *(ushort2*)&aggA[base] = make_ushort2(rne_bf16(r[0]), rne_bf16(r[1]));
}

// ---------------- layers 1-3 aggregation: gather bf16 activation rows ----------------
__global__ __launch_bounds__(256)
void k_agg16(const unsigned short* __restrict__ y16, const float* __restrict__ dis,
             const int* __restrict__ off, const int2* __restrict__ csre,
             unsigned short* __restrict__ aggA) {
  const int lane = threadIdx.x & 63;
  const int node = blockIdx.x * 4 + (threadIdx.x >> 6);  // wave per node
  const float di = dis[node];
  uint2 sv = *((const uint2*)(y16 + (size_t)node * HID) + lane);
  f32x4 a0 = di * cvt4(sv);
  f32x4 a1 = (f32x4)0.f, a2 = (f32x4)0.f, a3 = (f32x4)0.f;
  const int e0 = off[node], e1 = off[node + 1];
  int e = e0;
  for (; e + 4 <= e1; e += 4) {
    int2 c0 = csre[e], c1 = csre[e + 1], c2 = csre[e + 2], c3 = csre[e + 3];
    uint2 v0 = *((const uint2*)(y16 + (size_t)c0.x * HID) + lane);
    uint2 v1 = *((const uint2*)(y16 + (size_t)c1.x * HID) + lane);
    uint2 v2 = *((const uint2*)(y16 + (size_t)c2.x * HID) + lane);
    uint2 v3 = *((const uint2*)(y16 + (size_t)c3.x * HID) + lane);
    a0 += __int_as_float(c0.y) * cvt4(v0);
    a1 += __int_as_float(c1.y) * cvt4(v1);
    a2 += __int_as_float(c2.y) * cvt4(v2);
    a3 += __int_as_float(c3.y) * cvt4(v3);
  }
  for (; e < e1; ++e) {
    int2 c0 = csre[e];
    uint2 v0 = *((const uint2*)(y16 + (size_t)c0.x * HID) + lane);
    a0 += __int_as_float(c0.y) * cvt4(v0);
  }
  f32x4 r = di * ((a0 + a1) + (a2 + a3));
  size_t base = (size_t)node * HID + lane * 4;
  *(ushort4*)&aggA[base] = make_ushort4(rne_bf16(r[0]), rne_bf16(r[1]),
                                        rne_bf16(r[2]), rne_bf16(r[3]));
}

// ---------------- MFMA GEMM, 2-phase double-buffered staging (round-10 verbatim) ----------------
__device__ inline void gl_lds16(const void* g, void* l) {
  __builtin_amdgcn_global_load_lds((const __attribute__((address_space(1))) unsigned int*)g,
                                   (__attribute__((address_space(3))) unsigned int*)l,
                                   16, 0, 0);
}

template<int K>
__global__ __launch_bounds__(256)
void k_gemm_mfma(const unsigned short* __restrict__ Ah,
                 const unsigned short* __restrict__ Wh, const unsigned short* __restrict__ Wl,
                 const float* __restrict__ bias, unsigned short* __restrict__ C16) {
  __shared__ unsigned short sA[2][128 * 32];
  __shared__ unsigned short sBh[2][128 * 32];
  __shared__ unsigned short sBl[2][128 * 32];
  const int tid = threadIdx.x;
  const int lane = tid & 63;
  const int wid = tid >> 6;
  const int wr = wid >> 1, wc = wid & 1;
  const int row0 = blockIdx.x * 128;
  const int col0 = blockIdx.y * 128;
  const int cl = lane & 15;
  const int sl = lane >> 4;
  const int nt = K / 32;

  f32x4 acc[4][4];
  #pragma unroll
  for (int i = 0; i < 4; ++i)
    #pragma unroll
    for (int j = 0; j < 4; ++j) acc[i][j] = (f32x4)0.f;

  auto stage = [&](int b, int kt) {
    #pragma unroll
    for (int q = 0; q < 2; ++q) {
      int c = (wid * 2 + q) * 64 + lane;    // chunk id 0..511
      int row = c >> 2, slot = c & 3;
      int ss = slot ^ (row & 3);            // involution swizzle
      int ga = row0 + row; if (ga > N_NODES - 1) ga = N_NODES - 1;
      size_t aoff = (size_t)ga * K + kt + ss * 8;
      gl_lds16(Ah + aoff, &sA[b][(wid * 2 + q) * 512]);
      size_t boff = (size_t)(col0 + row) * K + kt + ss * 8;
      gl_lds16(Wh + boff, &sBh[b][(wid * 2 + q) * 512]);
      gl_lds16(Wl + boff, &sBl[b][(wid * 2 + q) * 512]);
    }
  };

  stage(0, 0);
  __syncthreads();

  for (int t = 0; t < nt; ++t) {
    const int cur = t & 1;
    if (t + 1 < nt) stage(cur ^ 1, (t + 1) * 32);   // prefetch under MFMA

    bf16x8 fa[4], fbh[4], fbl[4];
    #pragma unroll
    for (int f = 0; f < 4; ++f) {
      int ra = wr * 64 + f * 16 + cl;
      int oa = ra * 32 + ((sl ^ (ra & 3)) << 3);
      fa[f] = *(const bf16x8*)&sA[cur][oa];
      int rb = wc * 64 + f * 16 + cl;
      int ob = rb * 32 + ((sl ^ (rb & 3)) << 3);
      fbh[f] = *(const bf16x8*)&sBh[cur][ob];
      fbl[f] = *(const bf16x8*)&sBl[cur][ob];
    }
    #pragma unroll
    for (int i = 0; i < 4; ++i)
      #pragma unroll
      for (int j = 0; j < 4; ++j) {
        acc[i][j] = __builtin_amdgcn_mfma_f32_16x16x32_bf16(fa[i], fbh[j], acc[i][j], 0, 0, 0);
        acc[i][j] = __builtin_amdgcn_mfma_f32_16x16x32_bf16(fa[i], fbl[j], acc[i][j], 0, 0, 0);
      }
    __syncthreads();
  }

  #pragma unroll
  for (int j = 0; j < 4; ++j) {
    int gn = col0 + wc * 64 + j * 16 + cl;
    float bn = bias[gn];
    #pragma unroll
    for (int i = 0; i < 4; ++i) {
      f32x4 v = acc[i][j];
      #pragma unroll
      for (int r = 0; r < 4; ++r) {
        int gm = row0 + wr * 64 + i * 16 + sl * 4 + r;
        if (gm < N_NODES) C16[(size_t)gm * HID + gn] = rne_bf16(fmaxf(v[r] + bn, 0.f));
      }
    }
  }
}

// ---------------- pooling: 4 row-chunks per graph, atomic combine ----------------
__device__ inline int lower_bound_i(const int* a, int n, int v) {
  int lo = 0, hi = n;
  while (lo < hi) { int m = (lo + hi) >> 1; if (a[m] < v) lo = m + 1; else hi = m; }
  return lo;
}

__global__ __launch_bounds__(256)
void k_pool(const unsigned short* __restrict__ y16, const int* __restrict__ batch,
            float* __restrict__ gsum, float* __restrict__ gmax) {
  const int gi = blockIdx.x, ck = blockIdx.y, t = threadIdx.x;
  const int start = lower_bound_i(batch, N_NODES, gi);
  const int end   = lower_bound_i(batch, N_NODES, gi + 1);
  const int len = end - start;
  const int c0 = start + (len * ck) / 4;
  const int c1 = start + (len * (ck + 1)) / 4;
  float sum = 0.f, mx = 0.f;     // post-relu >= 0
  #pragma unroll 4
  for (int n = c0; n < c1; ++n) {
    float v = bf16_to_f32(y16[(size_t)n * HID + t]);
    sum += v; mx = fmaxf(mx, v);
  }
  if (c0 < c1) {
    atomicAdd(&gsum[gi * HID + t], sum);
    atomicMax((int*)&gmax[gi * HID + t], __float_as_int(mx));  // valid: mx >= 0
  }
}

// ---------------- classifier head ----------------
__global__ __launch_bounds__(256)
void k_cls(const float* __restrict__ gsum, const float* __restrict__ gmax,
           const int* __restrict__ batch,
           const float* __restrict__ Wc1, const float* __restrict__ bc1,
           const float* __restrict__ Wc2, const float* __restrict__ bc2,
           float* __restrict__ out) {
  const int gi = blockIdx.x, t = threadIdx.x;
  __shared__ float sg[512];
  __shared__ float sh[256];
  const int start = lower_bound_i(batch, N_NODES, gi);
  const int end   = lower_bound_i(batch, N_NODES, gi + 1);
  const float rcnt = 1.f / (float)((end - start) > 0 ? (end - start) : 1);
  sg[t] = gsum[gi * HID + t] * rcnt;
  sg[256 + t] = gmax[gi * HID + t];
  __syncthreads();
  float a = bc1[t];
  #pragma unroll 8
  for (int k = 0; k < 512; ++k) a = fmaf(sg[k], Wc1[k * HID + t], a);
  sh[t] = fmaxf(a, 0.f);
  __syncthreads();
  if (t < 2) {
    float o = bc2[t];
    for (int k = 0; k < 256; ++k) o = fmaf(sh[k], Wc2[k * 2 + t], o);
    out[gi * 2 + t] = o;
  }
}

// ---------------- launch ----------------
extern "C" void kernel_launch(void* const* d_in, const int* in_sizes, int n_in,
                              void* d_out, int out_size, void* d_ws, size_t ws_size,
                              hipStream_t stream) {
  const int*   x_ids = (const int*)d_in[0];
  const int*   ei    = (const int*)d_in[1];
  const int*   batch = (const int*)d_in[2];
  const float* emb   = (const float*)d_in[3];
  const float* W0 = (const float*)d_in[4];  const float* b0 = (const float*)d_in[5];
  const float* W1 = (const float*)d_in[6];  const float* b1 = (const float*)d_in[7];
  const float* W2 = (const float*)d_in[8];  const float* b2 = (const float*)d_in[9];
  const float* W3 = (const float*)d_in[10]; const float* b3 = (const float*)d_in[11];
  const float* Wc1 = (const float*)d_in[12]; const float* bc1 = (const float*)d_in[13];
  const float* Wc2 = (const float*)d_in[14]; const float* bc2 = (const float*)d_in[15];
  float* out = (float*)d_out;
  const int* src = ei;
  const int* dst = ei + N_EDGES;

  char* ws = (char*)d_ws;
  size_t o = 0;
  auto alloc = [&](size_t bytes) -> char* {
    char* p = ws + o; o += (bytes + 255) & ~(size_t)255; return p;
  };
  unsigned short* y16  = (unsigned short*)alloc((size_t)N_NODES * HID * 2);
  unsigned short* aggA = (unsigned short*)alloc((size_t)N_NODES * HID * 2);
  float* dis   = (float*)alloc((size_t)N_NODES * 4);
  int*   indeg = (int*)  alloc((size_t)N_NODES * 4);
  int*   off   = (int*)  alloc((size_t)(N_NODES + 1) * 4);
  int*   cur   = (int*)  alloc((size_t)(N_NODES + 1) * 4);
  int*   bsum  = (int*)  alloc((size_t)(NB_SCAN + 1) * 4);
  int2*  csre  = (int2*) alloc((size_t)N_EDGES * 8);
  unsigned short* emb16 = (unsigned short*)alloc((size_t)VOCAB * EMBD * 2);
  unsigned short* wbuf  = (unsigned short*)alloc((size_t)458752 * 2);
  float* gsum  = (float*)alloc((size_t)N_GRAPHS * HID * 4);
  float* gmax  = (float*)alloc((size_t)N_GRAPHS * HID * 4);
  (void)ws_size; (void)in_sizes; (void)n_in; (void)out_size;

  unsigned short* wt0h = wbuf;            unsigned short* wt0l = wbuf + 32768;
  unsigned short* wt1h = wbuf + 65536;    unsigned short* wt1l = wbuf + 131072;
  unsigned short* wt2h = wbuf + 196608;   unsigned short* wt2l = wbuf + 262144;
  unsigned short* wt3h = wbuf + 327680;   unsigned short* wt3l = wbuf + 393216;

  hipMemsetAsync(indeg, 0, (size_t)N_NODES * 4, stream);
  hipMemsetAsync(gsum, 0, (size_t)N_GRAPHS * HID * 4 * 2, stream);   // gsum+gmax contiguous
  k_indeg<<<N_EDGES / 256, 256, 0, stream>>>(dst, indeg);
  k_scan1<<<NB_SCAN, 1024, 0, stream>>>(indeg, off, bsum, dis);
  k_scan2<<<1, 128, 0, stream>>>(bsum);
  k_scan3<<<NB_SCAN, 1024, 0, stream>>>(off, cur, bsum);
  k_fill<<<N_EDGES / 256, 256, 0, stream>>>(src, dst, dis, cur, csre);
  k_prep<<<(VOCAB * EMBD + EMBD * HID + 3 * HID * HID + 255) / 256, 256, 0, stream>>>(
      emb, emb16, W0, wt0h, wt0l, W1, wt1h, wt1l, W2, wt2h, wt2l, W3, wt3h, wt3l);

  dim3 ggrid((N_NODES + 127) / 128, 2);
  // layer 0 (K = 128): csre -> ids -> emb16 (both L2-resident)
  k_agg0<<<N_NODES / 4, 256, 0, stream>>>(emb16, x_ids, dis, off, csre, aggA);
  k_gemm_mfma<128><<<ggrid, 256, 0, stream>>>(aggA, wt0h, wt0l, b0, y16);
  // layers 1..3 (K = 256): bf16 gather
  k_agg16<<<N_NODES / 4, 256, 0, stream>>>(y16, dis, off, csre, aggA);
  k_gemm_mfma<256><<<ggrid, 256, 0, stream>>>(aggA, wt1h, wt1l, b1, y16);
  k_agg16<<<N_NODES / 4, 256, 0, stream>>>(y16, dis, off, csre, aggA);
  k_gemm_mfma<256><<<ggrid, 256, 0, stream>>>(aggA, wt2h, wt2l, b2, y16);
  k_agg16<<<N_NODES / 4, 256, 0, stream>>>(y16, dis, off, csre, aggA);
  k_gemm_mfma<256><<<ggrid, 256, 0, stream>>>(aggA, wt3h, wt3l, b3, y16);

  dim3 pgrid(N_GRAPHS, 4);
  k_pool<<<pgrid, 256, 0, stream>>>(y16, batch, gsum, gmax);
  k_cls<<<N_GRAPHS, 256, 0, stream>>>(gsum, gmax, batch, Wc1, bc1, Wc2, bc2, out);
}